// Round 8
// baseline (425.332 us; speedup 1.0000x reference)
//
#include <hip/hip_runtime.h>

// Covariance: B=8, T=512, F=513, M=8, AVERAGE=True — single fused kernel.
constexpr int kB  = 8;
constexpr int kT  = 512;
constexpr int kF  = 513;
constexpr int kM  = 8;
constexpr int kNP = 36;          // M*(M+1)/2 pairs
constexpr int kC  = 2 * kNP;     // 72 floats per (b,t,f)
constexpr int kFT = 64;          // f-tile width (= wave)
constexpr int kNFT = 9;          // ceil(F/64)
constexpr int kNTC = 8;          // t-chunks (R1 best-known)
constexpr int kTC  = kT / kNTC;  // 64 t per chunk
constexpr int kLDP = kC + 1;     // LDS row pad
constexpr int kS4  = kF * kC / 4;                 // f4 per (b,t) slice = 9234
constexpr unsigned kBreg4  = (unsigned)kT * kS4;  // f4 per b = 4,727,808
constexpr unsigned kTotal4 = (unsigned)kB * kBreg4;  // 37,822,464
constexpr int kGrid    = kB * kNFT * kNTC;        // 576 blocks (co-resident)
constexpr int kThreads = kGrid * 256;             // 147,456
constexpr int kSweeps  = (int)((kTotal4 + kThreads - 1) / kThreads);  // 257
constexpr unsigned kGStep = (unsigned)kThreads / 18u;   // 8192 (g per sweep)
constexpr unsigned kTF    = (unsigned)kT * kF;          // 262,656
constexpr unsigned kFStep = kGStep % (unsigned)kF;      // 497

// Grid barrier: generation-counting, self-consistent across epochs.
// bar[0]=count, bar[1]=generation; zeroed by hipMemsetAsync each call.
__device__ __forceinline__ void gridbar(unsigned* bar, unsigned nb) {
  __syncthreads();
  if (threadIdx.x == 0) {
    __threadfence();   // device-scope release of this block's phase writes
    unsigned g = __hip_atomic_load(&bar[1], __ATOMIC_RELAXED,
                                   __HIP_MEMORY_SCOPE_AGENT);
    unsigned old = __hip_atomic_fetch_add(&bar[0], 1u, __ATOMIC_ACQ_REL,
                                          __HIP_MEMORY_SCOPE_AGENT);
    if (old == nb - 1u) {
      __hip_atomic_store(&bar[0], 0u, __ATOMIC_RELAXED,
                         __HIP_MEMORY_SCOPE_AGENT);
      __hip_atomic_fetch_add(&bar[1], 1u, __ATOMIC_RELEASE,
                             __HIP_MEMORY_SCOPE_AGENT);
    } else {
      while (__hip_atomic_load(&bar[1], __ATOMIC_ACQUIRE,
                               __HIP_MEMORY_SCOPE_AGENT) == g) {
        __builtin_amdgcn_s_sleep(2);
      }
    }
  }
  __syncthreads();
}

__global__ __launch_bounds__(256, 4)  // 4 blocks/CU -> all 576 co-resident
void cov_fused(const float* __restrict__ in, float* __restrict__ out,
               unsigned* __restrict__ bar) {
  const int tid  = threadIdx.x;
  const int wave = tid >> 6;
  const int lane = tid & 63;
  float4* __restrict__ out4 = (float4*)out;

  // ---------------- Phase 1: partial reduce (exact R1 pattern) -------------
  {
    const int bx = blockIdx.x;
    const int b  = bx / (kNFT * kNTC);
    const int r  = bx - b * (kNFT * kNTC);
    const int ft = r / kNTC;
    const int tc = r - ft * kNTC;
    const int f  = ft * kFT + lane;

    float accR[kNP], accI[kNP];
#pragma unroll
    for (int p = 0; p < kNP; ++p) { accR[p] = 0.0f; accI[p] = 0.0f; }

    if (f < kF) {
      const int t0 = tc * kTC + wave;
      const float* base = in + ((size_t)(b * kT + t0) * kF + f) * (2 * kM);
      const size_t tstep = (size_t)4 * kF * (2 * kM);   // advance 4 t's
      for (int it = 0; it < kTC / 4; ++it) {
        const float* ptr = base + it * tstep;
        const float4 r0 = *(const float4*)(ptr + 0);
        const float4 r1 = *(const float4*)(ptr + 4);
        const float4 i0 = *(const float4*)(ptr + 8);
        const float4 i1 = *(const float4*)(ptr + 12);
        const float re[kM] = {r0.x, r0.y, r0.z, r0.w, r1.x, r1.y, r1.z, r1.w};
        const float im[kM] = {i0.x, i0.y, i0.z, i0.w, i1.x, i1.y, i1.z, i1.w};
        int p = 0;
#pragma unroll
        for (int i = 0; i < kM; ++i) {
#pragma unroll
          for (int j = i; j < kM; ++j) {
            accR[p] += re[i] * re[j] + im[i] * im[j];
            accI[p] += re[i] * im[j] - im[i] * re[j];
            ++p;
          }
        }
      }
    }

    __shared__ float buf[2][kFT * kLDP];
    float* my = buf[wave & 1] + lane * kLDP;
    if (wave < 2) {
#pragma unroll
      for (int p = 0; p < kNP; ++p) { my[p] = accR[p]; my[kNP + p] = accI[p]; }
    }
    __syncthreads();
    if (wave >= 2) {
#pragma unroll
      for (int p = 0; p < kNP; ++p) { my[p] += accR[p]; my[kNP + p] += accI[p]; }
    }
    __syncthreads();

    const int nf = min(kFT, kF - ft * kFT);
    float* dst = out + ((size_t)(b * kT + (1 + tc)) * kF + ft * kFT) * kC;
    const int n = nf * kC;
    for (int e = tid; e < n; e += 256) {
      const int l = (unsigned)e / (unsigned)kC;
      const int p = e - l * kC;
      dst[e] = buf[0][l * kLDP + p] + buf[1][l * kLDP + p];
    }
  }

  gridbar(bar, (unsigned)gridDim.x);

  // ---------------- Phase 2: combine 8 partials -> mean at t=0 -------------
  {
    const unsigned idx0 = blockIdx.x * 256u + (unsigned)tid;
    if (idx0 < (unsigned)(kB * kS4)) {
      const unsigned b2 = idx0 / (unsigned)kS4;
      const unsigned fr = idx0 - b2 * (unsigned)kS4;
      const size_t base = (size_t)b2 * kBreg4;
      float4 s = make_float4(0.f, 0.f, 0.f, 0.f);
#pragma unroll
      for (int k = 0; k < kNTC; ++k) {
        const float4 v = out4[base + (size_t)(1 + k) * kS4 + fr];
        s.x += v.x; s.y += v.y; s.z += v.z; s.w += v.w;
      }
      const float sc = 1.0f / kT;
      s.x *= sc; s.y *= sc; s.z *= sc; s.w *= sc;
      out4[base + fr] = s;
    }
  }

  gridbar(bar, (unsigned)gridDim.x);

  // ---------------- Phase 3: linear broadcast (incremental indexing) -------
  {
    const unsigned idx0 = blockIdx.x * 256u + (unsigned)tid;
    const unsigned r = idx0 % 18u;        // f4-within-record: sweep-invariant
    const unsigned g0 = idx0 / 18u;       // record index (< 8192)
    unsigned gb = g0;                     // record index within batch b
    unsigned f  = g0 % (unsigned)kF;      // frequency index
    size_t srcb = 0;                      // b * kBreg4
    size_t dst  = idx0;
#pragma unroll 4
    for (int k = 0; k < kSweeps; ++k) {
      if (dst < (size_t)kTotal4)
        out4[dst] = out4[srcb + (size_t)f * 18u + r];  // t=0: benign self-copy
      dst += (size_t)kThreads;
      gb += kGStep;
      if (gb >= kTF) { gb -= kTF; srcb += kBreg4; }
      f += kFStep; if (f >= (unsigned)kF) f -= (unsigned)kF;
    }
  }
}

extern "C" void kernel_launch(void* const* d_in, const int* in_sizes, int n_in,
                              void* d_out, int out_size, void* d_ws, size_t ws_size,
                              hipStream_t stream) {
  const float* in = (const float*)d_in[0];
  float* out = (float*)d_out;
  unsigned* bar = (unsigned*)d_ws;

  hipMemsetAsync(d_ws, 0, 2 * sizeof(unsigned), stream);  // count, generation
  cov_fused<<<dim3(kGrid), dim3(256), 0, stream>>>(in, out, bar);
}

// Round 9
// 176.113 us; speedup vs baseline: 2.4151x; 2.4151x over previous
//
#include <hip/hip_runtime.h>

// Covariance: B=8, T=512, F=513, M=8, AVERAGE=True
constexpr int kB  = 8;
constexpr int kT  = 512;
constexpr int kF  = 513;
constexpr int kM  = 8;
constexpr int kNP = 36;          // M*(M+1)/2 pairs
constexpr int kC  = 2 * kNP;     // 72 floats per (b,t,f)
constexpr int kFT = 64;          // f-tile width (= wave)
constexpr int kNFT = 9;          // ceil(F/64)
constexpr int kNTC = 8;          // t-chunks (R1 best-known)
constexpr int kTC  = kT / kNTC;  // 64 t per chunk
constexpr int kLDP = kC + 1;     // LDS row pad
constexpr int kS4  = kF * kC / 4;                    // f4 per (b,t) slice = 9234
constexpr unsigned kBreg4  = (unsigned)kT * kS4;     // f4 per b = 4,727,808
constexpr unsigned kTotal4 = (unsigned)kB * kBreg4;  // 37,822,464
constexpr unsigned kTF     = (unsigned)kT * kF;      // records per b = 262,656

// Stage 1: R1's exact access pattern (measured best): lane = f (4KB contiguous
// per wave read), wave w on t-row t0+w, step 4, unroll 2 = 8 loads in flight.
// Combine folded in: scaled partials atomicAdd'ed into the pre-zeroed t=0
// mean slice (8 writers/address, 2.36M atomics total — trivial contention).
__global__ __launch_bounds__(256) void cov_partial(const float* __restrict__ in,
                                                   float* __restrict__ out) {
  const int bx = blockIdx.x;
  const int b  = bx / (kNFT * kNTC);
  const int r  = bx - b * (kNFT * kNTC);
  const int ft = r / kNTC;
  const int tc = r - ft * kNTC;
  const int tid  = threadIdx.x;
  const int wave = tid >> 6;
  const int lane = tid & 63;
  const int f = ft * kFT + lane;

  float accR[kNP], accI[kNP];
#pragma unroll
  for (int p = 0; p < kNP; ++p) { accR[p] = 0.0f; accI[p] = 0.0f; }

  if (f < kF) {
    const int t0 = tc * kTC + wave;
    const float* base = in + ((size_t)(b * kT + t0) * kF + f) * (2 * kM);
    const size_t tstep = (size_t)4 * kF * (2 * kM);   // advance 4 t's
#pragma unroll 2
    for (int it = 0; it < kTC / 4; ++it) {
      const float* ptr = base + it * tstep;
      const float4 r0 = *(const float4*)(ptr + 0);
      const float4 r1 = *(const float4*)(ptr + 4);
      const float4 i0 = *(const float4*)(ptr + 8);
      const float4 i1 = *(const float4*)(ptr + 12);
      const float re[kM] = {r0.x, r0.y, r0.z, r0.w, r1.x, r1.y, r1.z, r1.w};
      const float im[kM] = {i0.x, i0.y, i0.z, i0.w, i1.x, i1.y, i1.z, i1.w};
      int p = 0;
#pragma unroll
      for (int i = 0; i < kM; ++i) {
#pragma unroll
        for (int j = i; j < kM; ++j) {
          accR[p] += re[i] * re[j] + im[i] * im[j];
          accI[p] += re[i] * im[j] - im[i] * re[j];
          ++p;
        }
      }
    }
  }

  __shared__ float buf[2][kFT * kLDP];
  float* my = buf[wave & 1] + lane * kLDP;
  if (wave < 2) {
#pragma unroll
    for (int p = 0; p < kNP; ++p) { my[p] = accR[p]; my[kNP + p] = accI[p]; }
  }
  __syncthreads();
  if (wave >= 2) {
#pragma unroll
    for (int p = 0; p < kNP; ++p) { my[p] += accR[p]; my[kNP + p] += accI[p]; }
  }
  __syncthreads();

  // scaled atomic accumulate into the t=0 mean slice (pre-zeroed)
  const int nf = min(kFT, kF - ft * kFT);
  float* dst = out + ((size_t)b * kT * kF + ft * kFT) * kC;
  const int n = nf * kC;
  for (int e = tid; e < n; e += 256) {
    const int l = (unsigned)e / (unsigned)kC;
    const int p = e - l * kC;
    atomicAdd(&dst[e],
              (buf[0][l * kLDP + p] + buf[1][l * kLDP + p]) * (1.0f / kT));
  }
}

// Stage 2: broadcast t=0 slice to all t. Same LINEAR global write order as the
// measured-best R1 bcast, but 4 float4 per thread, wave-strided: store k writes
// lanes at [wbase + 64k, +64) -> contiguous 1KB per instruction, 4KB per wave.
// 4 independent loads issued before the 4 stores (no loop-carried alias chain).
__global__ __launch_bounds__(256) void cov_bcast(float4* __restrict__ out) {
  const unsigned gtid = blockIdx.x * 256u + threadIdx.x;
  const unsigned w    = gtid >> 6;              // global wave id
  const unsigned lane = threadIdx.x & 63u;
  const unsigned base = w * 256u + lane;        // first f4 for this thread
  unsigned src[4];
#pragma unroll
  for (int k = 0; k < 4; ++k) {
    const unsigned idx = base + 64u * k;
    const unsigned g = idx / 18u;               // record (b*T+t)*F + f
    const unsigned r = idx - g * 18u;           // f4 within record
    const unsigned b = g / kTF;
    const unsigned f = g % (unsigned)kF;
    src[k] = b * kBreg4 + f * 18u + r;          // mean slice at t=0
  }
  float4 v[4];
#pragma unroll
  for (int k = 0; k < 4; ++k) v[k] = out[src[k]];
#pragma unroll
  for (int k = 0; k < 4; ++k) out[base + 64u * k] = v[k];  // t=0: benign self-copy
}

extern "C" void kernel_launch(void* const* d_in, const int* in_sizes, int n_in,
                              void* d_out, int out_size, void* d_ws, size_t ws_size,
                              hipStream_t stream) {
  const float* in = (const float*)d_in[0];
  float* out = (float*)d_out;

  // zero the 8 t=0 mean slices (atomicAdd targets); capture-legal async memset
  for (int b = 0; b < kB; ++b)
    hipMemsetAsync(out + (size_t)b * kBreg4 * 4, 0, (size_t)kS4 * 16, stream);

  cov_partial<<<dim3(kB * kNFT * kNTC), dim3(256), 0, stream>>>(in, out);

  const unsigned nthreads = kTotal4 / 4u;       // 9,455,616 (exact)
  cov_bcast<<<dim3(nthreads / 256u), dim3(256), 0, stream>>>((float4*)out);
}